// Round 16
// baseline (119.653 us; speedup 1.0000x reference)
//
#include <hip/hip_runtime.h>
#include <math.h>

// ---------------------------------------------------------------------------
// NODE SEIAR, round 16 — r15 + issue-priority (setprio 3 integrators,
// s_sleep-paced burn).
//  * Numerics IDENTICAL to r10/r13/r15 (absmax 1.263618e-5): Tsit5-h4
//    transient [0,256] + RK4-h4 post-peak + RK4-h1 fine; gated checkless
//    packed-float4 sweeps (r15: 58.6us kernel).
//  * Method space closed by stability algebra: post-peak Jacobian fast mode
//    lambda~-0.77 near the peak -> h*lambda~-3.1; RK4-h4 is transiently
//    |R|~1.3-1.5 over a short window (survives on 1e-8 seeds — explains
//    r6/r8 blowups); RK3-h4 would be |R|~2.2 -> explode. T5-h4 + RK4-h4 is
//    the cheapest stable coarse pair.
//  * Remaining gap: chain runs ~8.3 cyc/dependent-FMA vs ~4-5 HW latency
//    (m07) — SIMD issue arbitration with always-ready burn/producer waves.
//    Fix: setprio(3) on integrator waves (latency-bound chain leaves idle
//    slots, so co-resident producers still progress on leftovers), and
//    s_sleep(2)-paced burn (48 FMAs / ~176 cyc ≈ 27% duty; r13 showed burn
//    width barely affects clock).
// ---------------------------------------------------------------------------

#define NCHUNK 32
#define NTOTAL 1280     // 5 blocks/CU x 256 CU, all co-resident
#define NPROD  (NTOTAL - NCHUNK)
#define BURN_MAX_POLLS 40000

// producer sections (consumption order)
#define NT5R   66                          // Tsit5 rows (64 + 2 pad)
#define TTOTAL (NT5R * 6 + 2 * 1023 + 1)   // + bi/bh interleaved + bi[1023]

// ws row allocs
#define ROWT_ALLOC 68     // stride 8
#define ROWC_ALLOC 200    // float4
#define ROWF_ALLOC 1032   // float4

// Tsit5 tableau
#define A21f 0.161f
#define A31f -0.008480655492356989f
#define A32f 0.335480655492357f
#define A41f 2.8971530571054935f
#define A42f -6.359448489975075f
#define A43f 4.3622954328695815f
#define A51f 5.325864828439257f
#define A52f -11.748883564062828f
#define A53f 7.4955393428898365f
#define A54f -0.09249506636175525f
#define A61f 5.86145544294642f
#define A62f -12.92096931784711f
#define A63f 8.159367898576159f
#define A64f -0.071584973281401f
#define A65f -0.028269050394068383f
#define B1f 0.09646076681806523f
#define B2f 0.01f
#define B3f 0.4798896504144996f
#define B4f 1.379008574103742f
#define B5f -3.290069515436081f
#define B6f 2.324710524099774f

typedef float v2f __attribute__((ext_vector_type(2)));
__device__ __forceinline__ v2f vfma(v2f a, v2f b, v2f c) {
    return __builtin_elementwise_fma(a, b, c);
}
__device__ __forceinline__ v2f splat2(float x) { return (v2f){x, x}; }

struct Bounds { int s[NCHUNK + 1]; };

__device__ const float g_cstage[6] = {
    0.0f, 0.161f, 0.327f, 0.9f, 0.9800255409045097f, 1.0f};

__device__ __forceinline__ float softplus_f(float x) {
    return fmaxf(x, 0.0f) + log1pf(expf(-fabsf(x)));
}
__device__ __forceinline__ int imin(int a, int b) { return a < b ? a : b; }

// SEIAR constants
#define cKK  0.526f
#define cAA  0.244f
#define cII  0.244f
#define cPKK ((float)(0.667 * 0.526))
#define cQKK ((float)((1.0 - 0.667) * 0.526))
#define cFAA ((float)(0.98 * 0.244))

__device__ __forceinline__ void rhs2(v2f zSE, v2f zIA, float b,
                                     v2f& kSE, v2f& kIA, float& kR) {
    float S = zSE.x, E = zSE.y, I = zIA.x, A = zIA.y;
    float LL = fmaf(0.5f, I, A);
    float T  = (b * S) * LL;
    kSE = (v2f){-T, fmaf(-cKK, E, T)};
    kIA = (v2f){fmaf(cPKK, E, -cAA * I), fmaf(cQKK, E, -cII * A)};
    kR  = fmaf(cFAA, I, cII * A);
}

struct Tab2 {
    v2f a21,a31,a32,a41,a42,a43,a51,a52,a53,a54;
    v2f a61,a62,a63,a64,a65,b1,b2,b3,b4,b5,b6;
};
__device__ __forceinline__ Tab2 make_tab2(float h) {
    Tab2 t;
    t.a21=splat2(A21f*h); t.a31=splat2(A31f*h); t.a32=splat2(A32f*h);
    t.a41=splat2(A41f*h); t.a42=splat2(A42f*h); t.a43=splat2(A43f*h);
    t.a51=splat2(A51f*h); t.a52=splat2(A52f*h); t.a53=splat2(A53f*h);
    t.a54=splat2(A54f*h); t.a61=splat2(A61f*h); t.a62=splat2(A62f*h);
    t.a63=splat2(A63f*h); t.a64=splat2(A64f*h); t.a65=splat2(A65f*h);
    t.b1=splat2(B1f*h); t.b2=splat2(B2f*h); t.b3=splat2(B3f*h);
    t.b4=splat2(B4f*h); t.b5=splat2(B5f*h); t.b6=splat2(B6f*h);
    return t;
}

#define FOLD(dSE,dIA,dR, c, kSE,kIA,kR, pSE,pIA,pR) \
    dSE = vfma(T.c, kSE, pSE); dIA = vfma(T.c, kIA, pIA); \
    dR  = fmaf(T.c.x, kR, pR);

// Tsit5 step, newest-k-last (bit-identical to r10/r13/r15).
__device__ __forceinline__ void t5_step(v2f& zSE, v2f& zIA, float& zR,
                                        const Tab2& T, const float bc[6]) {
    v2f k1SE,k1IA,k2SE,k2IA,k3SE,k3IA,k4SE,k4IA,k5SE,k5IA,k6SE,k6IA;
    float k1R,k2R,k3R,k4R,k5R,k6R;
    v2f tSE,tIA,pSE,pIA; float tR,pR;

    rhs2(zSE,zIA,bc[0],k1SE,k1IA,k1R);
    FOLD(tSE,tIA,tR, a21, k1SE,k1IA,k1R, zSE,zIA,zR);
    rhs2(tSE,tIA,bc[1],k2SE,k2IA,k2R);
    FOLD(pSE,pIA,pR, a31, k1SE,k1IA,k1R, zSE,zIA,zR);
    FOLD(tSE,tIA,tR, a32, k2SE,k2IA,k2R, pSE,pIA,pR);
    rhs2(tSE,tIA,bc[2],k3SE,k3IA,k3R);
    FOLD(pSE,pIA,pR, a41, k1SE,k1IA,k1R, zSE,zIA,zR);
    FOLD(pSE,pIA,pR, a42, k2SE,k2IA,k2R, pSE,pIA,pR);
    FOLD(tSE,tIA,tR, a43, k3SE,k3IA,k3R, pSE,pIA,pR);
    rhs2(tSE,tIA,bc[3],k4SE,k4IA,k4R);
    FOLD(pSE,pIA,pR, a51, k1SE,k1IA,k1R, zSE,zIA,zR);
    FOLD(pSE,pIA,pR, a52, k2SE,k2IA,k2R, pSE,pIA,pR);
    FOLD(pSE,pIA,pR, a53, k3SE,k3IA,k3R, pSE,pIA,pR);
    FOLD(tSE,tIA,tR, a54, k4SE,k4IA,k4R, pSE,pIA,pR);
    rhs2(tSE,tIA,bc[4],k5SE,k5IA,k5R);
    FOLD(pSE,pIA,pR, a61, k1SE,k1IA,k1R, zSE,zIA,zR);
    FOLD(pSE,pIA,pR, a62, k2SE,k2IA,k2R, pSE,pIA,pR);
    FOLD(pSE,pIA,pR, a63, k3SE,k3IA,k3R, pSE,pIA,pR);
    FOLD(pSE,pIA,pR, a64, k4SE,k4IA,k4R, pSE,pIA,pR);
    FOLD(tSE,tIA,tR, a65, k5SE,k5IA,k5R, pSE,pIA,pR);
    rhs2(tSE,tIA,bc[5],k6SE,k6IA,k6R);
    FOLD(pSE,pIA,pR, b1, k1SE,k1IA,k1R, zSE,zIA,zR);
    FOLD(pSE,pIA,pR, b2, k2SE,k2IA,k2R, pSE,pIA,pR);
    FOLD(pSE,pIA,pR, b3, k3SE,k3IA,k3R, pSE,pIA,pR);
    FOLD(pSE,pIA,pR, b4, k4SE,k4IA,k4R, pSE,pIA,pR);
    FOLD(pSE,pIA,pR, b5, k5SE,k5IA,k5R, pSE,pIA,pR);
    FOLD(zSE,zIA,zR, b6, k6SE,k6IA,k6R, pSE,pIA,pR);
}

// RK4 step (bit-identical to r10/r13/r15).
__device__ __forceinline__ void rk4_step(v2f& zSE, v2f& zIA, float& zR,
                                         v2f h2v, v2f hv, v2f h6v,
                                         float b0, float bm, float b1) {
    v2f k1SE,k1IA,k2SE,k2IA,k3SE,k3IA,k4SE,k4IA;
    float k1R,k2R,k3R,k4R;
    v2f tSE,tIA; float tR;
    const v2f two = splat2(2.0f);

    rhs2(zSE,zIA,b0,k1SE,k1IA,k1R);
    tSE=vfma(h2v,k1SE,zSE); tIA=vfma(h2v,k1IA,zIA); tR=fmaf(h2v.x,k1R,zR);
    rhs2(tSE,tIA,bm,k2SE,k2IA,k2R);
    tSE=vfma(h2v,k2SE,zSE); tIA=vfma(h2v,k2IA,zIA); tR=fmaf(h2v.x,k2R,zR);
    rhs2(tSE,tIA,bm,k3SE,k3IA,k3R);
    tSE=vfma(hv,k3SE,zSE);  tIA=vfma(hv,k3IA,zIA);  tR=fmaf(hv.x,k3R,zR);
    v2f PSE = vfma(two, k2SE + k3SE, k1SE);
    v2f PIA = vfma(two, k2IA + k3IA, k1IA);
    float PR = fmaf(2.0f, k2R + k3R, k1R);
    rhs2(tSE,tIA,b1,k4SE,k4IA,k4R);
    zSE = vfma(h6v, PSE + k4SE, zSE);
    zIA = vfma(h6v, PIA + k4IA, zIA);
    zR  = fmaf(h6v.x, PR + k4R, zR);
}

__device__ __forceinline__ float aload(const float* p) {
    return __hip_atomic_load(p, __ATOMIC_RELAXED, __HIP_MEMORY_SCOPE_AGENT);
}

// Gate: all 64 lanes verify comps 0..2 of float4 rows [0..n), then acquire.
__device__ __forceinline__ void gate3(const float4* rows, int n, int lane) {
    for (;;) {
        bool ok = true;
        for (int r = lane; r < n; r += 64) {
            const float* p = (const float*)(rows + r);
            ok &= (aload(p) > 0.0f) && (aload(p+1) > 0.0f) && (aload(p+2) > 0.0f);
        }
        if (__all(ok)) break;
        __builtin_amdgcn_s_sleep(2);
    }
    __builtin_amdgcn_fence(__ATOMIC_ACQUIRE, "agent");
}
// Gate for stride-8 6-comp Tsit5 rows [0..n).
__device__ __forceinline__ void gate6(const float* rowT, int n, int lane) {
    for (;;) {
        bool ok = true;
        for (int r = lane; r < n; r += 64) {
            const float* p = rowT + r * 8;
            ok &= (aload(p)>0.f) && (aload(p+1)>0.f) && (aload(p+2)>0.f)
               && (aload(p+3)>0.f) && (aload(p+4)>0.f) && (aload(p+5)>0.f);
        }
        if (__all(ok)) break;
        __builtin_amdgcn_s_sleep(2);
    }
    __builtin_amdgcn_fence(__ATOMIC_ACQUIRE, "agent");
}

__global__ __launch_bounds__(64, 1) void fused_kernel(
    const float* __restrict__ ts,
    const float* __restrict__ state_vec,
    const float* __restrict__ w_in, const float* __restrict__ b_in,
    const float* __restrict__ w_h,  const float* __restrict__ b_h,
    const float* __restrict__ w_out, const float* __restrict__ b_out,
    float* __restrict__ rowT, float4* __restrict__ rowC,
    float4* __restrict__ rowF,
    float* __restrict__ done_arr, float* __restrict__ out,
    Bounds B)
{
    int b    = blockIdx.x;
    int lane = threadIdx.x;

    if (b >= NCHUNK) {
        // ================= producer, then paced burn =================
        int p = b - NCHUNK;
        float t0g = ts[0], hf = ts[1] - ts[0];
        float wi = w_in[lane], bi_ = b_in[lane];
        float bhh = b_h[lane], wo = w_out[lane];
        float bo = b_out[0];
        const float* __restrict__ wr = w_h + (lane << 6);
        float* rowCf = (float*)rowC;
        float* rowFf = (float*)rowF;

        for (int e = p; e < TTOTAL; e += NPROD) {
            float t; int kind, i = 0;
            if (e < NT5R * 6) { kind = 0;
                int row = e / 6, st = e - row * 6;
                t = t0g + (4.0f * row + 4.0f * g_cstage[st]) * hf;
            } else if (e < NT5R * 6 + 2 * 1023) {
                int idx = e - NT5R * 6; i = idx >> 1;
                if (idx & 1) { kind = 2; t = t0g + ((float)i + 0.5f) * hf; }
                else         { kind = 1; t = t0g + (float)i * hf; }
            } else { kind = 1; i = 1023; t = t0g + 1023.0f * hf; }

            float h1 = softplus_f(fmaf(wi, t, bi_));
            float acc = bhh;
#pragma unroll
            for (int k = 0; k < 64; ++k)
                acc = fmaf(wr[k], __shfl(h1, k, 64), acc);
            float h2 = softplus_f(acc);
            float pr = wo * h2;
#pragma unroll
            for (int off = 32; off > 0; off >>= 1)
                pr += __shfl_down(pr, off, 64);
            if (lane == 0) {
                float o  = pr + bo;
                float bb = 1.0f / (1.0f + expf(-1e-4f * o));   // in (0,1)
#define ASTORE(ptr) __hip_atomic_store((ptr), bb, __ATOMIC_RELAXED, \
                                       __HIP_MEMORY_SCOPE_AGENT)
                if (kind == 0) {
                    ASTORE(rowT + (e / 6) * 8 + (e % 6));
                } else if (kind == 1) {                 // bi[i]
                    if (i <= 1022) ASTORE(rowFf + i * 4 + 0);
                    if (i >= 1)    ASTORE(rowFf + (i - 1) * 4 + 2);
                    if (i >= 256) {
                        int d = i - 256;
                        if ((d & 3) == 0) {             // beta(256+4j)
                            int j = d >> 2;
                            if (j < ROWC_ALLOC) ASTORE(rowCf + j * 4 + 0);
                            if (j >= 1)         ASTORE(rowCf + (j - 1) * 4 + 2);
                        } else if ((d & 3) == 2) {      // beta(258+4j)
                            int j = (d - 2) >> 2;
                            if (j < ROWC_ALLOC) ASTORE(rowCf + j * 4 + 1);
                        }
                    }
                } else {                                // bh[i]
                    ASTORE(rowFf + i * 4 + 1);
                }
#undef ASTORE
            }
        }

        // paced burn: 48 FMAs + s_sleep(2) per poll (~27% issue duty).
        // Keeps SMU activity (r13: burn width barely moves clock) while
        // freeing SIMD issue slots for the latency-bound integrator chains.
        float x[8];
#pragma unroll
        for (int j = 0; j < 8; ++j) x[j] = 1.0f + (float)(lane + j) * 1e-12f;
        for (int outer = 0; outer < BURN_MAX_POLLS; ++outer) {
            for (int i2 = 0; i2 < 6; ++i2) {
#pragma unroll
                for (int j = 0; j < 8; ++j)
                    x[j] = fmaf(x[j], 0.99999988f, 1e-9f);
            }
            __builtin_amdgcn_s_sleep(2);
            float f = aload(done_arr + (lane & 31));
            if (__all(f == 1.0f)) break;
        }
        float r = 0.0f;
#pragma unroll
        for (int j = 0; j < 8; ++j) r += x[j];
        if (r == 123456.0f) done_arr[63] = r;
        return;
    }

    // ================= integrator block b =================
    // Highest wave priority: the chain is latency-bound and leaves idle
    // issue slots, so co-resident producers still progress on leftovers.
    __builtin_amdgcn_s_setprio(3);

    int start = B.s[b];
    int end   = B.s[b + 1];
    int nf    = end - start;
    float hf  = ts[1] - ts[0];
    int nc    = start >> 2;           // starts are multiples of 4
    int nT    = imin(nc, 64);
    int nR    = nc - nT;              // RK4-h4 steps from t=256

    // z0 = softmax(state_vec) (lane 0 registers)
    v2f zSE, zIA; float zR;
    if (lane == 0) {
        float v[5], zz[5];
#pragma unroll
        for (int s = 0; s < 5; ++s) v[s] = state_vec[s];
        float m = v[0];
#pragma unroll
        for (int s = 1; s < 5; ++s) m = fmaxf(m, v[s]);
        float sum = 0.0f;
#pragma unroll
        for (int s = 0; s < 5; ++s) { zz[s] = expf(v[s] - m); sum += zz[s]; }
        float inv = 1.0f / sum;
#pragma unroll
        for (int s = 0; s < 5; ++s) zz[s] *= inv;
        zSE = (v2f){zz[0], zz[1]}; zIA = (v2f){zz[2], zz[3]}; zR = zz[4];
        if (b == 0) {
#pragma unroll
            for (int s = 0; s < 5; ++s) out[s] = zz[s];
        }
    }

    if (nf > 0) {
        // ---- Tsit5-h4 transient replay (gated, checkless) ----
        if (nT > 0) {
            gate6(rowT, nT, lane);
            if (lane == 0) {
                Tab2 T = make_tab2(4.0f * hf);
                float4 q0 = *(const float4*)(rowT);
                float2 s0 = *(const float2*)(rowT + 4);
                float4 q1 = *(const float4*)(rowT + 8);
                float2 s1 = *(const float2*)(rowT + 12);
                int i = 0;
                for (; i + 2 <= nT; i += 2) {
                    float bc[6] = {q0.x,q0.y,q0.z,q0.w,s0.x,s0.y};
                    q0 = *(const float4*)(rowT + (i + 2) * 8);
                    s0 = *(const float2*)(rowT + (i + 2) * 8 + 4);
                    t5_step(zSE, zIA, zR, T, bc);
                    float bd[6] = {q1.x,q1.y,q1.z,q1.w,s1.x,s1.y};
                    q1 = *(const float4*)(rowT + (i + 3) * 8);
                    s1 = *(const float2*)(rowT + (i + 3) * 8 + 4);
                    t5_step(zSE, zIA, zR, T, bd);
                }
                if (i < nT) {
                    float bc[6] = {q0.x,q0.y,q0.z,q0.w,s0.x,s0.y};
                    t5_step(zSE, zIA, zR, T, bc);
                }
            }
        }

        // ---- RK4-h4 post-peak replay (gated, checkless) ----
        if (nR > 0) {
            gate3(rowC, nR, lane);
            if (lane == 0) {
                v2f h2v = splat2(2.0f * hf), hv = splat2(4.0f * hf),
                    h6v = splat2(4.0f * hf / 6.0f);
                float4 c0 = rowC[0], c1 = rowC[1],
                       c2 = rowC[2], c3 = rowC[3];
                int j = 0;
                for (; j + 4 <= nR; j += 4) {
                    float4 u;
                    u = c0; c0 = rowC[j + 4];
                    rk4_step(zSE,zIA,zR,h2v,hv,h6v,u.x,u.y,u.z);
                    u = c1; c1 = rowC[j + 5];
                    rk4_step(zSE,zIA,zR,h2v,hv,h6v,u.x,u.y,u.z);
                    u = c2; c2 = rowC[j + 6];
                    rk4_step(zSE,zIA,zR,h2v,hv,h6v,u.x,u.y,u.z);
                    u = c3; c3 = rowC[j + 7];
                    rk4_step(zSE,zIA,zR,h2v,hv,h6v,u.x,u.y,u.z);
                }
                if (j < nR) { rk4_step(zSE,zIA,zR,h2v,hv,h6v,c0.x,c0.y,c0.z); j++; }
                if (j < nR) { rk4_step(zSE,zIA,zR,h2v,hv,h6v,c1.x,c1.y,c1.z); j++; }
                if (j < nR) { rk4_step(zSE,zIA,zR,h2v,hv,h6v,c2.x,c2.y,c2.z); j++; }
            }
        }

        // ---- fine RK4-h1 sweep (gated, checkless), store each interval ----
        gate3(rowF + start, nf, lane);
        if (lane == 0) {
            v2f h2v = splat2(0.5f * hf), hv = splat2(hf),
                h6v = splat2(hf * (1.0f / 6.0f));
            const float4* RF = rowF + start;
            float4 r0 = RF[0], r1 = RF[1], r2 = RF[2], r3 = RF[3];
            int i = 0;
#define FSTORE(ii) { \
            float* op = out + (size_t)(start + (ii) + 1) * 5; \
            op[0]=zSE.x; op[1]=zSE.y; op[2]=zIA.x; op[3]=zIA.y; op[4]=zR; }
            for (; i + 4 <= nf; i += 4) {
                float4 u;
                u = r0; r0 = RF[i + 4];
                rk4_step(zSE,zIA,zR,h2v,hv,h6v,u.x,u.y,u.z); FSTORE(i)
                u = r1; r1 = RF[i + 5];
                rk4_step(zSE,zIA,zR,h2v,hv,h6v,u.x,u.y,u.z); FSTORE(i + 1)
                u = r2; r2 = RF[i + 6];
                rk4_step(zSE,zIA,zR,h2v,hv,h6v,u.x,u.y,u.z); FSTORE(i + 2)
                u = r3; r3 = RF[i + 7];
                rk4_step(zSE,zIA,zR,h2v,hv,h6v,u.x,u.y,u.z); FSTORE(i + 3)
            }
            if (i < nf) { rk4_step(zSE,zIA,zR,h2v,hv,h6v,r0.x,r0.y,r0.z);
                          FSTORE(i) i++; }
            if (i < nf) { rk4_step(zSE,zIA,zR,h2v,hv,h6v,r1.x,r1.y,r1.z);
                          FSTORE(i) i++; }
            if (i < nf) { rk4_step(zSE,zIA,zR,h2v,hv,h6v,r2.x,r2.y,r2.z);
                          FSTORE(i) i++; }
#undef FSTORE
        }
    }

    if (lane == 0)
        __hip_atomic_store(done_arr + b, 1.0f, __ATOMIC_RELAXED,
                           __HIP_MEMORY_SCOPE_AGENT);
}

extern "C" void kernel_launch(void* const* d_in, const int* in_sizes, int n_in,
                              void* d_out, int out_size, void* d_ws, size_t ws_size,
                              hipStream_t stream)
{
    // 0 y0_ignored(5) 1 ts(1024) 2 state_vec(5) 3 w_in(64) 4 b_in(64)
    // 5 w_h(4096) 6 b_h(64) 7 w_out(64) 8 b_out(1) 9 scales(5)  [all f32]
    const float* ts        = (const float*)d_in[1];
    const float* state_vec = (const float*)d_in[2];
    const float* w_in      = (const float*)d_in[3];
    const float* b_in      = (const float*)d_in[4];
    const float* w_h       = (const float*)d_in[5];
    const float* b_h       = (const float*)d_in[6];
    const float* w_out     = (const float*)d_in[7];
    const float* b_out     = (const float*)d_in[8];
    float* out = (float*)d_out;

    int n_int = in_sizes[1] - 1;                  // 1023

    // Balanced bounds, cycle units (r15 verbatim): T5-h4 75/interval
    // (<=256), RK4-h4 45/interval (>256), fine RK4-h1 200/interval.
    const float cT = 75.f, cR = 45.f, cF = 200.f;
    auto costR = [&](float s) {
        float a = s < 256.f ? s : 256.f;
        float c = s > 256.f ? s - 256.f : 0.f;
        return cT * a + cR * c;
    };
    auto nextS = [&](float D, int s) {
        float f = (D - costR((float)s)) / cF;
        int fi = ((int)(f / 4.f)) * 4;
        if (fi < 4) fi = 4;
        int s2 = s + fi;
        if (s2 > n_int) s2 = n_int;
        return s2;
    };
    auto cover = [&](float D) {
        int s = 0;
        for (int bb = 0; bb < NCHUNK; ++bb) s = nextS(D, s);
        return s;
    };
    float lo = 800.f, hi = 300000.f;
    for (int it = 0; it < 48; ++it) {
        float mid = 0.5f * (lo + hi);
        if (cover(mid) >= n_int) hi = mid; else lo = mid;
    }
    float D = hi;
    Bounds B;
    {
        int s = 0; B.s[0] = 0;
        for (int bb = 0; bb < NCHUNK; ++bb) {
            s = nextS(D, s);
            B.s[bb + 1] = s;
        }
        B.s[NCHUNK] = n_int;
    }

    // Workspace (floats): done_arr 64 | rowT 68*8 | rowC 200*4 | rowF 1032*4
    float* done_arr = (float*)d_ws;
    float* rowT     = done_arr + 64;
    float4* rowC    = (float4*)(rowT + (size_t)ROWT_ALLOC * 8);
    float4* rowF    = rowC + ROWC_ALLOC;

    fused_kernel<<<NTOTAL, 64, 0, stream>>>(
        ts, state_vec, w_in, b_in, w_h, b_h, w_out, b_out,
        rowT, rowC, rowF, done_arr, out, B);
}